// Round 6
// baseline (205.015 us; speedup 1.0000x reference)
//
#include <hip/hip_runtime.h>
#include <hip/hip_bf16.h>
#include <math.h>

typedef __attribute__((ext_vector_type(8))) short short8;
typedef __attribute__((ext_vector_type(4))) float f32x4;

#define NUM_TABLES 26
#define ROWS 100000
#define EMB 64
#define BATCH 4096
#define LOOKUPS 32
#define ZDIM 1728  // 64*(1+26)

#define CAST_BLOCKS 128
#define BOT_BLOCKS 256                       // 16 batch rows each
#define EMBED_BLOCKS (NUM_TABLES * BATCH / 4)

__device__ __forceinline__ unsigned short f2bf(float f) {
  unsigned int u = __float_as_uint(f);
  u += 0x7FFFu + ((u >> 16) & 1u);   // round-to-nearest-even
  return (unsigned short)(u >> 16);
}
__device__ __forceinline__ float bf2f(unsigned short h) {
  return __uint_as_float(((unsigned int)h) << 16);
}

__device__ __forceinline__ void gload16(const void* g, void* l) {
  __builtin_amdgcn_global_load_lds(
      (const __attribute__((address_space(1))) void*)g,
      (__attribute__((address_space(3))) void*)l, 16, 0, 0);
}

// B-fragment for mfma_16x16x32_bf16 straight from an f32 weight matrix W[N][K]:
// lane l holds W[colbase + (l&15)][kc*32 + (l>>4)*8 + j], j=0..7, converted bf16.
__device__ __forceinline__ short8 wfrag_f32(const float* __restrict__ W, int K,
                                            int colbase, int l, int kc) {
  const float* p = W + (size_t)(colbase + (l & 15)) * K + kc * 32 + ((l >> 4) << 3);
  float4 u = *(const float4*)p;
  float4 v = *(const float4*)(p + 4);
  short8 f;
  f[0] = (short)f2bf(u.x); f[1] = (short)f2bf(u.y);
  f[2] = (short)f2bf(u.z); f[3] = (short)f2bf(u.w);
  f[4] = (short)f2bf(v.x); f[5] = (short)f2bf(v.y);
  f[6] = (short)f2bf(v.z); f[7] = (short)f2bf(v.w);
  return f;
}

struct MegaArgs {
  const float* cast_s[2];           // tw0, tw1
  unsigned short* cast_d[2];
  int cast_n4[2];
  int cast_total;
  const float* x_dense;
  const float* bw0; const float* bb0;
  const float* bw1; const float* bb1;
  const float* bw2; const float* bb2;
  const int* idx;
  const float* tables;
  unsigned short* z;
};

// ---- mega kernel: 3 block roles ----
// [0, CAST_BLOCKS): cast top weights f32->bf16
// [CAST_BLOCKS, +BOT_BLOCKS): bottom MLP for 16 batch rows, block-local
// rest: EmbeddingBag sum (wave per bag)
__global__ void mega(MegaArgs a) {
  __shared__ unsigned short xb[16][256];   // x bf16, then h1 (bot1 out)
  __shared__ unsigned short h0[16][512];   // bot0 out

  if (blockIdx.x < CAST_BLOCKS) {
    for (int i = blockIdx.x * blockDim.x + threadIdx.x; i < a.cast_total;
         i += CAST_BLOCKS * blockDim.x) {
      int r = i;
      #pragma unroll
      for (int sg = 0; sg < 2; ++sg) {
        if (r < a.cast_n4[sg]) {
          float4 v = ((const float4*)a.cast_s[sg])[r];
          ushort4 o;
          o.x = f2bf(v.x); o.y = f2bf(v.y); o.z = f2bf(v.z); o.w = f2bf(v.w);
          ((ushort4*)a.cast_d[sg])[r] = o;
          break;
        }
        r -= a.cast_n4[sg];
      }
    }
    return;
  }

  if (blockIdx.x < CAST_BLOCKS + BOT_BLOCKS) {
    // ---- bottom MLP role: rows [b0, b0+16) ----
    int b0 = (int)(blockIdx.x - CAST_BLOCKS) << 4;
    int w = threadIdx.x >> 6;       // wave 0..3
    int l = threadIdx.x & 63;

    // stage x f32 -> bf16 LDS, XOR-swizzled 16B chunks: chunk' = chunk ^ (row&7)
    #pragma unroll
    for (int i = 0; i < 4; ++i) {
      int flat = i * 256 + threadIdx.x;     // float4 id, 0..1023
      int row = flat >> 6;                  // 64 float4 per row
      int c4 = flat & 63;
      float4 v = *(const float4*)(a.x_dense + (size_t)(b0 + row) * 256 + c4 * 4);
      int chunk = c4 >> 1;
      int scol = ((chunk ^ (row & 7)) << 3) | ((c4 & 1) << 2);
      ushort4 o;
      o.x = f2bf(v.x); o.y = f2bf(v.y); o.z = f2bf(v.z); o.w = f2bf(v.w);
      *(ushort4*)&xb[row][scol] = o;
    }
    __syncthreads();

    int arow = l & 15;
    int sA = arow & 7;
    const char* xbp = (const char*)&xb[0][0];
    const char* h0p = (const char*)&h0[0][0];

    // ---- bot0: h0[16][512] = relu(x @ W0^T + b0), K=256 ----
    f32x4 acc0[8];
    #pragma unroll
    for (int n = 0; n < 8; ++n) acc0[n] = (f32x4){0.f, 0.f, 0.f, 0.f};
    for (int kc = 0; kc < 8; ++kc) {
      int c = kc * 4 + (l >> 4);
      short8 av = *(const short8*)(xbp + arow * 512 + ((c ^ sA) << 4));
      #pragma unroll
      for (int n = 0; n < 8; ++n) {
        short8 bv = wfrag_f32(a.bw0, 256, w * 128 + n * 16, l, kc);
        acc0[n] = __builtin_amdgcn_mfma_f32_16x16x32_bf16(av, bv, acc0[n], 0, 0, 0);
      }
    }
    #pragma unroll
    for (int n = 0; n < 8; ++n) {
      int col = w * 128 + n * 16 + (l & 15);
      float bv = a.bb0[col];
      int chunk = col >> 3;
      #pragma unroll
      for (int r = 0; r < 4; ++r) {
        int row = ((l >> 4) << 2) + r;
        float val = acc0[n][r] + bv;
        val = val > 0.f ? val : 0.f;
        h0[row][((chunk ^ (row & 7)) << 3) | (col & 7)] = f2bf(val);
      }
    }
    __syncthreads();

    // ---- bot1: h1[16][256] = relu(h0 @ W1^T + b1), K=512 -> into xb ----
    f32x4 acc1[4];
    #pragma unroll
    for (int n = 0; n < 4; ++n) acc1[n] = (f32x4){0.f, 0.f, 0.f, 0.f};
    for (int kc = 0; kc < 16; ++kc) {
      int c = kc * 4 + (l >> 4);
      short8 av = *(const short8*)(h0p + arow * 1024 + ((c ^ sA) << 4));
      #pragma unroll
      for (int n = 0; n < 4; ++n) {
        short8 bv = wfrag_f32(a.bw1, 512, w * 64 + n * 16, l, kc);
        acc1[n] = __builtin_amdgcn_mfma_f32_16x16x32_bf16(av, bv, acc1[n], 0, 0, 0);
      }
    }
    __syncthreads();     // everyone done reading xb before overwrite
    #pragma unroll
    for (int n = 0; n < 4; ++n) {
      int col = w * 64 + n * 16 + (l & 15);
      float bv = a.bb1[col];
      int chunk = col >> 3;
      #pragma unroll
      for (int r = 0; r < 4; ++r) {
        int row = ((l >> 4) << 2) + r;
        float val = acc1[n][r] + bv;
        val = val > 0.f ? val : 0.f;
        xb[row][((chunk ^ (row & 7)) << 3) | (col & 7)] = f2bf(val);
      }
    }
    __syncthreads();

    // ---- bot2: z[b,0:64] = relu(h1 @ W2^T + b2), K=256 ----
    f32x4 acc2 = (f32x4){0.f, 0.f, 0.f, 0.f};
    for (int kc = 0; kc < 8; ++kc) {
      int c = kc * 4 + (l >> 4);
      short8 av = *(const short8*)(xbp + arow * 512 + ((c ^ sA) << 4));
      short8 bv = wfrag_f32(a.bw2, 256, w * 16, l, kc);
      acc2 = __builtin_amdgcn_mfma_f32_16x16x32_bf16(av, bv, acc2, 0, 0, 0);
    }
    {
      int col = w * 16 + (l & 15);
      float bv = a.bb2[col];
      #pragma unroll
      for (int r = 0; r < 4; ++r) {
        int row = ((l >> 4) << 2) + r;
        float val = acc2[r] + bv;
        val = val > 0.f ? val : 0.f;
        a.z[(size_t)(b0 + row) * ZDIM + col] = f2bf(val);
      }
    }
    return;
  }

  // ---- embedding role: one wave per bag, float4/lane, 4 rows/iter ----
  int g = (int)(((blockIdx.x - CAST_BLOCKS - BOT_BLOCKS) << 2) + (threadIdx.x >> 6));
  int lane = threadIdx.x & 63;
  int t = g >> 12;          // / BATCH
  int b = g & 4095;
  const int* ip = a.idx + ((size_t)t * BATCH + b) * LOOKUPS;
  int myidx = (lane < LOOKUPS) ? ip[lane] : 0;
  const float* tbl = a.tables + (size_t)t * ROWS * EMB;
  int grp = lane >> 4;      // lookup sub-group 0..3
  int e4 = lane & 15;       // float4 index within row
  float4 acc = {0.f, 0.f, 0.f, 0.f};
  #pragma unroll
  for (int it = 0; it < 8; ++it) {
    int r = __shfl(myidx, it * 4 + grp, 64);
    float4 v = ((const float4*)(tbl + (size_t)r * EMB))[e4];
    acc.x += v.x; acc.y += v.y; acc.z += v.z; acc.w += v.w;
  }
  #pragma unroll
  for (int m = 16; m <= 32; m <<= 1) {
    acc.x += __shfl_xor(acc.x, m, 64);
    acc.y += __shfl_xor(acc.y, m, 64);
    acc.z += __shfl_xor(acc.z, m, 64);
    acc.w += __shfl_xor(acc.w, m, 64);
  }
  if (lane < 16) {
    ushort4 o;
    o.x = f2bf(acc.x); o.y = f2bf(acc.y); o.z = f2bf(acc.z); o.w = f2bf(acc.w);
    *(ushort4*)&a.z[(size_t)b * ZDIM + EMB + t * EMB + e4 * 4] = o;
  }
}

// ---- top0 GEMM: z1[4096][512] = relu(z @ tw0b^T + tb0), K=1728 ----
// 128x64 tile / 256-thread block -> 256 blocks (1 per CU). m97 single-buffer
// schedule; global_load_lds width-16; XOR bank-swizzle via pre-swizzled source.
// Wave (wr,wc): wr=wid>>1 owns 64 A-rows, wc=wid&1 owns 32 B-rows -> 4x2 frags.
__global__ __launch_bounds__(256) void gemm_top0(
    const unsigned short* __restrict__ A,
    const unsigned short* __restrict__ W,
    const float* __restrict__ bias,
    unsigned short* __restrict__ C) {
  const int K = ZDIM, ldc = 512;
  __shared__ unsigned short ldsA[128][64];  // 16 KiB
  __shared__ unsigned short ldsB[64][64];   //  8 KiB

  int t = threadIdx.x;
  int lane = t & 63;
  int wid = t >> 6;
  int wr = wid >> 1;        // 0..1
  int wc = wid & 1;         // 0..1

  int tm = blockIdx.x >> 3;        // 32 row-tiles
  int tn = blockIdx.x & 7;         // 8 col-tiles

  int srow = lane >> 3;                    // 0..7
  int schunk = (lane & 7) ^ srow;          // pre-swizzled global chunk
  const unsigned short* Ap0 = A + (size_t)(tm * 128 + wid * 32 + srow) * K + schunk * 8;
  const unsigned short* Wp0 = W + (size_t)(tn * 64 + wid * 16 + srow) * K + schunk * 8;
  size_t rowK8 = (size_t)8 * K;

  f32x4 acc[4][2];
  #pragma unroll
  for (int m = 0; m < 4; ++m)
    #pragma unroll
    for (int n = 0; n < 2; ++n)
      acc[m][n] = (f32x4){0.f, 0.f, 0.f, 0.f};

  int rb = wc * 32 + (lane & 15);
  int cidx = lane >> 4;
  int sB = rb & 7;

  for (int k0 = 0; k0 < K; k0 += 64) {
    #pragma unroll
    for (int j = 0; j < 4; ++j)
      gload16(Ap0 + (size_t)k0 + j * rowK8, &ldsA[wid * 32 + j * 8][0]);
    #pragma unroll
    for (int j = 0; j < 2; ++j)
      gload16(Wp0 + (size_t)k0 + j * rowK8, &ldsB[wid * 16 + j * 8][0]);
    __syncthreads();          // vmcnt(0) drain: stage landed

    const char* bA = (const char*)&ldsA[0][0];
    const char* bB = (const char*)&ldsB[0][0];
    #pragma unroll
    for (int kc = 0; kc < 2; ++kc) {
      int c = kc * 4 + cidx;
      short8 b0 = *(const short8*)(bB + rb * 128 + ((c ^ sB) << 4));
      short8 b1 = *(const short8*)(bB + (rb + 16) * 128 + ((c ^ ((rb + 16) & 7)) << 4));
      #pragma unroll
      for (int m = 0; m < 4; ++m) {
        int ra = wr * 64 + m * 16 + (lane & 15);
        short8 av = *(const short8*)(bA + ra * 128 + ((c ^ (ra & 7)) << 4));
        acc[m][0] = __builtin_amdgcn_mfma_f32_16x16x32_bf16(av, b0, acc[m][0], 0, 0, 0);
        acc[m][1] = __builtin_amdgcn_mfma_f32_16x16x32_bf16(av, b1, acc[m][1], 0, 0, 0);
      }
    }
    __syncthreads();          // reads done before next stage
  }

  #pragma unroll
  for (int m = 0; m < 4; ++m) {
    int drow = tm * 128 + wr * 64 + m * 16 + ((lane >> 4) << 2);
    #pragma unroll
    for (int n = 0; n < 2; ++n) {
      int dcol = tn * 64 + wc * 32 + n * 16 + (lane & 15);
      float bv = bias[dcol];
      #pragma unroll
      for (int r = 0; r < 4; ++r) {
        float v = acc[m][n][r] + bv;
        v = v > 0.f ? v : 0.f;
        C[(size_t)(drow + r) * ldc + dcol] = f2bf(v);
      }
    }
  }
}

// ---- fused top1 + final: per block 64 rows; wave computes its 16 rows x all
// 256 cols of relu(z1 @ tw1b^T + tb1) in registers, then dots with tw2 and
// applies sigmoid via in-register 16-lane reduction. No LDS, no z2 buffer. ----
__global__ __launch_bounds__(256) void topfin(
    const unsigned short* __restrict__ z1,   // [4096][512] bf16
    const unsigned short* __restrict__ w1,   // [256][512] bf16
    const float* __restrict__ b1,            // [256]
    const float* __restrict__ w2,            // [256]
    const float* __restrict__ b2,            // [1]
    float* __restrict__ out) {
  int l = threadIdx.x & 63;
  int wid = threadIdx.x >> 6;
  int row0 = (int)blockIdx.x * 64 + wid * 16;

  f32x4 acc[16];
  #pragma unroll
  for (int n = 0; n < 16; ++n) acc[n] = (f32x4){0.f, 0.f, 0.f, 0.f};

  const unsigned short* ap0 = z1 + (size_t)(row0 + (l & 15)) * 512 + ((l >> 4) << 3);
  #pragma unroll 2
  for (int kc = 0; kc < 16; ++kc) {
    short8 av = *(const short8*)(ap0 + kc * 32);
    #pragma unroll
    for (int n = 0; n < 16; ++n) {
      const unsigned short* bp = w1 + (size_t)(n * 16 + (l & 15)) * 512 + kc * 32 + ((l >> 4) << 3);
      short8 bv = *(const short8*)bp;
      acc[n] = __builtin_amdgcn_mfma_f32_16x16x32_bf16(av, bv, acc[n], 0, 0, 0);
    }
  }

  // bias + relu + dot with w2 (all f32, in registers)
  float s0 = 0.f, s1 = 0.f, s2 = 0.f, s3 = 0.f;
  #pragma unroll
  for (int n = 0; n < 16; ++n) {
    int col = n * 16 + (l & 15);
    float bv = b1[col];
    float wv = w2[col];
    float v0 = acc[n][0] + bv; v0 = v0 > 0.f ? v0 : 0.f; s0 += v0 * wv;
    float v1 = acc[n][1] + bv; v1 = v1 > 0.f ? v1 : 0.f; s1 += v1 * wv;
    float v2 = acc[n][2] + bv; v2 = v2 > 0.f ? v2 : 0.f; s2 += v2 * wv;
    float v3 = acc[n][3] + bv; v3 = v3 > 0.f ? v3 : 0.f; s3 += v3 * wv;
  }
  // reduce across the 16 lanes of each (l>>4) group
  #pragma unroll
  for (int m = 1; m <= 8; m <<= 1) {
    s0 += __shfl_xor(s0, m, 64);
    s1 += __shfl_xor(s1, m, 64);
    s2 += __shfl_xor(s2, m, 64);
    s3 += __shfl_xor(s3, m, 64);
  }
  if ((l & 15) == 0) {
    int r0 = row0 + (l >> 4) * 4;
    float bb = b2[0];
    out[r0 + 0] = 1.f / (1.f + expf(-(s0 + bb)));
    out[r0 + 1] = 1.f / (1.f + expf(-(s1 + bb)));
    out[r0 + 2] = 1.f / (1.f + expf(-(s2 + bb)));
    out[r0 + 3] = 1.f / (1.f + expf(-(s3 + bb)));
  }
}

extern "C" void kernel_launch(void* const* d_in, const int* in_sizes, int n_in,
                              void* d_out, int out_size, void* d_ws, size_t ws_size,
                              hipStream_t stream) {
  const float* x_dense = (const float*)d_in[0];
  const int*   x_idx   = (const int*)d_in[1];
  const float* tables  = (const float*)d_in[2];
  const float* bw0 = (const float*)d_in[3];  const float* bb0 = (const float*)d_in[4];
  const float* bw1 = (const float*)d_in[5];  const float* bb1 = (const float*)d_in[6];
  const float* bw2 = (const float*)d_in[7];  const float* bb2 = (const float*)d_in[8];
  const float* tw0 = (const float*)d_in[9];  const float* tb0 = (const float*)d_in[10];
  const float* tw1 = (const float*)d_in[11]; const float* tb1 = (const float*)d_in[12];
  const float* tw2 = (const float*)d_in[13]; const float* tb2 = (const float*)d_in[14];
  float* out = (float*)d_out;

  char* ws = (char*)d_ws;
  size_t off = 0;
  auto alloc = [&](size_t bytes) { void* p = ws + off; off += (bytes + 255) & ~(size_t)255; return p; };
  unsigned short* tw0b = (unsigned short*)alloc((size_t)512 * ZDIM * 2);
  unsigned short* tw1b = (unsigned short*)alloc((size_t)256 * 512 * 2);
  unsigned short* z    = (unsigned short*)alloc((size_t)BATCH * ZDIM * 2);
  unsigned short* z1   = (unsigned short*)alloc((size_t)BATCH * 512 * 2);

  // mega: cast(tw0,tw1) + bottom MLP (z[:,0:64]) + embedding (z[:,64:])
  {
    MegaArgs a;
    a.cast_s[0] = tw0; a.cast_d[0] = tw0b; a.cast_n4[0] = 512 * ZDIM / 4;
    a.cast_s[1] = tw1; a.cast_d[1] = tw1b; a.cast_n4[1] = 256 * 512 / 4;
    a.cast_total = a.cast_n4[0] + a.cast_n4[1];
    a.x_dense = x_dense;
    a.bw0 = bw0; a.bb0 = bb0;
    a.bw1 = bw1; a.bb1 = bb1;
    a.bw2 = bw2; a.bb2 = bb2;
    a.idx = x_idx;
    a.tables = tables;
    a.z = z;
    mega<<<CAST_BLOCKS + BOT_BLOCKS + EMBED_BLOCKS, 256, 0, stream>>>(a);
  }

  // top0: z1 = relu(z @ tw0b^T + tb0)  [M=4096, N=512, K=1728]
  gemm_top0<<<256, 256, 0, stream>>>(z, tw0b, tb0, z1);

  // top1 + final fused
  topfin<<<BATCH / 64, 256, 0, stream>>>(z1, tw1b, tb1, tw2, tb2, out);
}

// Round 7
// 174.927 us; speedup vs baseline: 1.1720x; 1.1720x over previous
//
#include <hip/hip_runtime.h>
#include <hip/hip_bf16.h>
#include <math.h>

typedef __attribute__((ext_vector_type(8))) short short8;
typedef __attribute__((ext_vector_type(4))) float f32x4;

#define NUM_TABLES 26
#define ROWS 100000
#define EMB 64
#define BATCH 4096
#define LOOKUPS 32
#define ZDIM 1728  // 64*(1+26)

#define CAST_BLOCKS 128
#define BOT_BLOCKS 256                       // 16 batch rows each
#define EMBED_BLOCKS (NUM_TABLES * BATCH / 4)

__device__ __forceinline__ unsigned short f2bf(float f) {
  unsigned int u = __float_as_uint(f);
  u += 0x7FFFu + ((u >> 16) & 1u);   // round-to-nearest-even
  return (unsigned short)(u >> 16);
}
__device__ __forceinline__ float bf2f(unsigned short h) {
  return __uint_as_float(((unsigned int)h) << 16);
}

__device__ __forceinline__ void gload16(const void* g, void* l) {
  __builtin_amdgcn_global_load_lds(
      (const __attribute__((address_space(1))) void*)g,
      (__attribute__((address_space(3))) void*)l, 16, 0, 0);
}

// B-fragment for mfma_16x16x32_bf16 straight from an f32 weight matrix W[N][K]:
// lane l holds W[colbase + (l&15)][kc*32 + (l>>4)*8 + j], j=0..7, converted bf16.
__device__ __forceinline__ short8 wfrag_f32(const float* __restrict__ W, int K,
                                            int colbase, int l, int kc) {
  const float* p = W + (size_t)(colbase + (l & 15)) * K + kc * 32 + ((l >> 4) << 3);
  float4 u = *(const float4*)p;
  float4 v = *(const float4*)(p + 4);
  short8 f;
  f[0] = (short)f2bf(u.x); f[1] = (short)f2bf(u.y);
  f[2] = (short)f2bf(u.z); f[3] = (short)f2bf(u.w);
  f[4] = (short)f2bf(v.x); f[5] = (short)f2bf(v.y);
  f[6] = (short)f2bf(v.z); f[7] = (short)f2bf(v.w);
  return f;
}

struct MegaArgs {
  const float* cast_s[2];           // tw0, tw1
  unsigned short* cast_d[2];
  int cast_n4[2];
  int cast_total;
  const float* x_dense;
  const float* bw0; const float* bb0;
  const float* bw1; const float* bb1;
  const float* bw2; const float* bb2;
  const int* idx;
  const float* tables;
  unsigned short* z;
};

// ---- mega kernel: 3 block roles (UNCHANGED from R5 — proven) ----
__global__ void mega(MegaArgs a) {
  __shared__ unsigned short xb[16][256];   // x bf16, then h1 (bot1 out)
  __shared__ unsigned short h0[16][512];   // bot0 out

  if (blockIdx.x < CAST_BLOCKS) {
    for (int i = blockIdx.x * blockDim.x + threadIdx.x; i < a.cast_total;
         i += CAST_BLOCKS * blockDim.x) {
      int r = i;
      #pragma unroll
      for (int sg = 0; sg < 2; ++sg) {
        if (r < a.cast_n4[sg]) {
          float4 v = ((const float4*)a.cast_s[sg])[r];
          ushort4 o;
          o.x = f2bf(v.x); o.y = f2bf(v.y); o.z = f2bf(v.z); o.w = f2bf(v.w);
          ((ushort4*)a.cast_d[sg])[r] = o;
          break;
        }
        r -= a.cast_n4[sg];
      }
    }
    return;
  }

  if (blockIdx.x < CAST_BLOCKS + BOT_BLOCKS) {
    // ---- bottom MLP role: rows [b0, b0+16) ----
    int b0 = (int)(blockIdx.x - CAST_BLOCKS) << 4;
    int w = threadIdx.x >> 6;       // wave 0..3
    int l = threadIdx.x & 63;

    #pragma unroll
    for (int i = 0; i < 4; ++i) {
      int flat = i * 256 + threadIdx.x;     // float4 id, 0..1023
      int row = flat >> 6;                  // 64 float4 per row
      int c4 = flat & 63;
      float4 v = *(const float4*)(a.x_dense + (size_t)(b0 + row) * 256 + c4 * 4);
      int chunk = c4 >> 1;
      int scol = ((chunk ^ (row & 7)) << 3) | ((c4 & 1) << 2);
      ushort4 o;
      o.x = f2bf(v.x); o.y = f2bf(v.y); o.z = f2bf(v.z); o.w = f2bf(v.w);
      *(ushort4*)&xb[row][scol] = o;
    }
    __syncthreads();

    int arow = l & 15;
    int sA = arow & 7;
    const char* xbp = (const char*)&xb[0][0];
    const char* h0p = (const char*)&h0[0][0];

    // ---- bot0: h0[16][512] = relu(x @ W0^T + b0), K=256 ----
    f32x4 acc0[8];
    #pragma unroll
    for (int n = 0; n < 8; ++n) acc0[n] = (f32x4){0.f, 0.f, 0.f, 0.f};
    for (int kc = 0; kc < 8; ++kc) {
      int c = kc * 4 + (l >> 4);
      short8 av = *(const short8*)(xbp + arow * 512 + ((c ^ sA) << 4));
      #pragma unroll
      for (int n = 0; n < 8; ++n) {
        short8 bv = wfrag_f32(a.bw0, 256, w * 128 + n * 16, l, kc);
        acc0[n] = __builtin_amdgcn_mfma_f32_16x16x32_bf16(av, bv, acc0[n], 0, 0, 0);
      }
    }
    #pragma unroll
    for (int n = 0; n < 8; ++n) {
      int col = w * 128 + n * 16 + (l & 15);
      float bv = a.bb0[col];
      int chunk = col >> 3;
      #pragma unroll
      for (int r = 0; r < 4; ++r) {
        int row = ((l >> 4) << 2) + r;
        float val = acc0[n][r] + bv;
        val = val > 0.f ? val : 0.f;
        h0[row][((chunk ^ (row & 7)) << 3) | (col & 7)] = f2bf(val);
      }
    }
    __syncthreads();

    // ---- bot1: h1[16][256] = relu(h0 @ W1^T + b1), K=512 -> into xb ----
    f32x4 acc1[4];
    #pragma unroll
    for (int n = 0; n < 4; ++n) acc1[n] = (f32x4){0.f, 0.f, 0.f, 0.f};
    for (int kc = 0; kc < 16; ++kc) {
      int c = kc * 4 + (l >> 4);
      short8 av = *(const short8*)(h0p + arow * 1024 + ((c ^ sA) << 4));
      #pragma unroll
      for (int n = 0; n < 4; ++n) {
        short8 bv = wfrag_f32(a.bw1, 512, w * 64 + n * 16, l, kc);
        acc1[n] = __builtin_amdgcn_mfma_f32_16x16x32_bf16(av, bv, acc1[n], 0, 0, 0);
      }
    }
    __syncthreads();     // everyone done reading xb before overwrite
    #pragma unroll
    for (int n = 0; n < 4; ++n) {
      int col = w * 64 + n * 16 + (l & 15);
      float bv = a.bb1[col];
      int chunk = col >> 3;
      #pragma unroll
      for (int r = 0; r < 4; ++r) {
        int row = ((l >> 4) << 2) + r;
        float val = acc1[n][r] + bv;
        val = val > 0.f ? val : 0.f;
        xb[row][((chunk ^ (row & 7)) << 3) | (col & 7)] = f2bf(val);
      }
    }
    __syncthreads();

    // ---- bot2: z[b,0:64] = relu(h1 @ W2^T + b2), K=256 ----
    f32x4 acc2 = (f32x4){0.f, 0.f, 0.f, 0.f};
    for (int kc = 0; kc < 8; ++kc) {
      int c = kc * 4 + (l >> 4);
      short8 av = *(const short8*)(xbp + arow * 512 + ((c ^ sA) << 4));
      short8 bv = wfrag_f32(a.bw2, 256, w * 16, l, kc);
      acc2 = __builtin_amdgcn_mfma_f32_16x16x32_bf16(av, bv, acc2, 0, 0, 0);
    }
    {
      int col = w * 16 + (l & 15);
      float bv = a.bb2[col];
      #pragma unroll
      for (int r = 0; r < 4; ++r) {
        int row = ((l >> 4) << 2) + r;
        float val = acc2[r] + bv;
        val = val > 0.f ? val : 0.f;
        a.z[(size_t)(b0 + row) * ZDIM + col] = f2bf(val);
      }
    }
    return;
  }

  // ---- embedding role: one wave per bag, float4/lane, 4 rows/iter ----
  int g = (int)(((blockIdx.x - CAST_BLOCKS - BOT_BLOCKS) << 2) + (threadIdx.x >> 6));
  int lane = threadIdx.x & 63;
  int t = g >> 12;          // / BATCH
  int b = g & 4095;
  const int* ip = a.idx + ((size_t)t * BATCH + b) * LOOKUPS;
  int myidx = (lane < LOOKUPS) ? ip[lane] : 0;
  const float* tbl = a.tables + (size_t)t * ROWS * EMB;
  int grp = lane >> 4;      // lookup sub-group 0..3
  int e4 = lane & 15;       // float4 index within row
  float4 acc = {0.f, 0.f, 0.f, 0.f};
  #pragma unroll
  for (int it = 0; it < 8; ++it) {
    int r = __shfl(myidx, it * 4 + grp, 64);
    float4 v = ((const float4*)(tbl + (size_t)r * EMB))[e4];
    acc.x += v.x; acc.y += v.y; acc.z += v.z; acc.w += v.w;
  }
  #pragma unroll
  for (int m = 16; m <= 32; m <<= 1) {
    acc.x += __shfl_xor(acc.x, m, 64);
    acc.y += __shfl_xor(acc.y, m, 64);
    acc.z += __shfl_xor(acc.z, m, 64);
    acc.w += __shfl_xor(acc.w, m, 64);
  }
  if (lane < 16) {
    ushort4 o;
    o.x = f2bf(acc.x); o.y = f2bf(acc.y); o.z = f2bf(acc.z); o.w = f2bf(acc.w);
    *(ushort4*)&a.z[(size_t)b * ZDIM + EMB + t * EMB + e4 * 4] = o;
  }
}

// ---- block GEMM (m97 single-buffer schedule, R4-proven): 64x64 tile ----
// + bijective XCD-chunked blockIdx swizzle (grid must be divisible by 8).
template<int ACT>  // 0 = none, 1 = relu
__global__ __launch_bounds__(256) void gemm64s(
    const unsigned short* __restrict__ A,
    const unsigned short* __restrict__ W,
    const float* __restrict__ bias,
    unsigned short* __restrict__ C,
    int M, int N, int K, int ldc) {
  __shared__ unsigned short lds[2][64][64];  // [A=0/B=1][row][col], 16 KiB

  int t = threadIdx.x;
  int lane = t & 63;
  int wid = t >> 6;
  int wr = wid >> 1;        // 0..1
  int wc = wid & 1;         // 0..1

  // XCD swizzle: XCD (bid&7) gets a contiguous chunk of tile ids -> shared
  // A-panels stay in that XCD's L2. Bijective because gridDim.x % 8 == 0.
  int bid = (int)blockIdx.x;
  int q = (int)gridDim.x >> 3;
  int swz = (bid & 7) * q + (bid >> 3);

  int ntn = N >> 6;
  int tm = swz / ntn;
  int tn = swz - tm * ntn;

  int srow = lane >> 3;
  int schunk = (lane & 7) ^ (srow & 7);
  const unsigned short* Ap0 = A + (size_t)(tm * 64 + wid * 16 + srow) * K + schunk * 8;
  const unsigned short* Wp0 = W + (size_t)(tn * 64 + wid * 16 + srow) * K + schunk * 8;
  size_t rowK8 = (size_t)8 * K;

  f32x4 acc[2][2];
  #pragma unroll
  for (int m = 0; m < 2; ++m)
    #pragma unroll
    for (int n = 0; n < 2; ++n)
      acc[m][n] = (f32x4){0.f, 0.f, 0.f, 0.f};

  int ra = wr * 32 + (lane & 15);
  int rb = wc * 32 + (lane & 15);
  int cidx = lane >> 4;
  int sA = ra & 7, sB = rb & 7;

  for (int k0 = 0; k0 < K; k0 += 64) {
    #pragma unroll
    for (int j = 0; j < 2; ++j) {
      gload16(Ap0 + (size_t)k0 + j * rowK8, &lds[0][wid * 16 + j * 8][0]);
      gload16(Wp0 + (size_t)k0 + j * rowK8, &lds[1][wid * 16 + j * 8][0]);
    }
    __syncthreads();

    const char* bA = (const char*)&lds[0][0][0];
    const char* bB = (const char*)&lds[1][0][0];
    #pragma unroll
    for (int kc = 0; kc < 2; ++kc) {
      int c = kc * 4 + cidx;
      short8 a0 = *(const short8*)(bA + ra * 128 + ((c ^ sA) << 4));
      short8 a1 = *(const short8*)(bA + (ra + 16) * 128 + ((c ^ sA) << 4));
      short8 b0 = *(const short8*)(bB + rb * 128 + ((c ^ sB) << 4));
      short8 b1 = *(const short8*)(bB + (rb + 16) * 128 + ((c ^ sB) << 4));
      acc[0][0] = __builtin_amdgcn_mfma_f32_16x16x32_bf16(a0, b0, acc[0][0], 0, 0, 0);
      acc[0][1] = __builtin_amdgcn_mfma_f32_16x16x32_bf16(a0, b1, acc[0][1], 0, 0, 0);
      acc[1][0] = __builtin_amdgcn_mfma_f32_16x16x32_bf16(a1, b0, acc[1][0], 0, 0, 0);
      acc[1][1] = __builtin_amdgcn_mfma_f32_16x16x32_bf16(a1, b1, acc[1][1], 0, 0, 0);
    }
    __syncthreads();
  }

  #pragma unroll
  for (int m = 0; m < 2; ++m) {
    int drow = tm * 64 + wr * 32 + m * 16 + ((lane >> 4) << 2);
    #pragma unroll
    for (int n = 0; n < 2; ++n) {
      int dcol = tn * 64 + wc * 32 + n * 16 + (lane & 15);
      float bv = bias[dcol];
      #pragma unroll
      for (int r = 0; r < 4; ++r) {
        float v = acc[m][n][r] + bv;
        if (ACT == 1) v = v > 0.f ? v : 0.f;
        C[(size_t)(drow + r) * ldc + dcol] = f2bf(v);
      }
    }
  }
}

// ---- fused top1 + final, 256 blocks x 16 rows: wave w computes cols
// [w*64,(w+1)*64) of relu(z1 @ w1^T + b1) in registers, dots with w2,
// 16-lane shfl reduce + tiny LDS cross-wave reduce, sigmoid, store. ----
__global__ __launch_bounds__(256) void topfin256(
    const unsigned short* __restrict__ z1,   // [4096][512] bf16
    const unsigned short* __restrict__ w1,   // [256][512] bf16
    const float* __restrict__ b1,            // [256]
    const float* __restrict__ w2,            // [256]
    const float* __restrict__ b2,            // [1]
    float* __restrict__ out) {
  __shared__ float red[4][16];
  int l = threadIdx.x & 63;
  int w = threadIdx.x >> 6;
  int row0 = (int)blockIdx.x * 16;

  f32x4 acc[4];
  #pragma unroll
  for (int n = 0; n < 4; ++n) acc[n] = (f32x4){0.f, 0.f, 0.f, 0.f};

  const unsigned short* ap0 = z1 + (size_t)(row0 + (l & 15)) * 512 + ((l >> 4) << 3);
  const unsigned short* bp0 = w1 + (size_t)(w * 64 + (l & 15)) * 512 + ((l >> 4) << 3);
  #pragma unroll 4
  for (int kc = 0; kc < 16; ++kc) {
    short8 av = *(const short8*)(ap0 + kc * 32);
    #pragma unroll
    for (int n = 0; n < 4; ++n) {
      short8 bv = *(const short8*)(bp0 + (size_t)n * 16 * 512 + kc * 32);
      acc[n] = __builtin_amdgcn_mfma_f32_16x16x32_bf16(av, bv, acc[n], 0, 0, 0);
    }
  }

  // bias + relu + dot with w2 over this wave's 64 cols
  float s0 = 0.f, s1 = 0.f, s2 = 0.f, s3 = 0.f;
  #pragma unroll
  for (int n = 0; n < 4; ++n) {
    int col = w * 64 + n * 16 + (l & 15);
    float bv = b1[col];
    float wv = w2[col];
    float v0 = acc[n][0] + bv; v0 = v0 > 0.f ? v0 : 0.f; s0 += v0 * wv;
    float v1 = acc[n][1] + bv; v1 = v1 > 0.f ? v1 : 0.f; s1 += v1 * wv;
    float v2 = acc[n][2] + bv; v2 = v2 > 0.f ? v2 : 0.f; s2 += v2 * wv;
    float v3 = acc[n][3] + bv; v3 = v3 > 0.f ? v3 : 0.f; s3 += v3 * wv;
  }
  #pragma unroll
  for (int m = 1; m <= 8; m <<= 1) {
    s0 += __shfl_xor(s0, m, 64);
    s1 += __shfl_xor(s1, m, 64);
    s2 += __shfl_xor(s2, m, 64);
    s3 += __shfl_xor(s3, m, 64);
  }
  if ((l & 15) == 0) {
    int rbase = (l >> 4) * 4;
    red[w][rbase + 0] = s0;
    red[w][rbase + 1] = s1;
    red[w][rbase + 2] = s2;
    red[w][rbase + 3] = s3;
  }
  __syncthreads();
  if (threadIdx.x < 16) {
    float s = red[0][threadIdx.x] + red[1][threadIdx.x] +
              red[2][threadIdx.x] + red[3][threadIdx.x];
    out[row0 + threadIdx.x] = 1.f / (1.f + expf(-(s + b2[0])));
  }
}

extern "C" void kernel_launch(void* const* d_in, const int* in_sizes, int n_in,
                              void* d_out, int out_size, void* d_ws, size_t ws_size,
                              hipStream_t stream) {
  const float* x_dense = (const float*)d_in[0];
  const int*   x_idx   = (const int*)d_in[1];
  const float* tables  = (const float*)d_in[2];
  const float* bw0 = (const float*)d_in[3];  const float* bb0 = (const float*)d_in[4];
  const float* bw1 = (const float*)d_in[5];  const float* bb1 = (const float*)d_in[6];
  const float* bw2 = (const float*)d_in[7];  const float* bb2 = (const float*)d_in[8];
  const float* tw0 = (const float*)d_in[9];  const float* tb0 = (const float*)d_in[10];
  const float* tw1 = (const float*)d_in[11]; const float* tb1 = (const float*)d_in[12];
  const float* tw2 = (const float*)d_in[13]; const float* tb2 = (const float*)d_in[14];
  float* out = (float*)d_out;

  char* ws = (char*)d_ws;
  size_t off = 0;
  auto alloc = [&](size_t bytes) { void* p = ws + off; off += (bytes + 255) & ~(size_t)255; return p; };
  unsigned short* tw0b = (unsigned short*)alloc((size_t)512 * ZDIM * 2);
  unsigned short* tw1b = (unsigned short*)alloc((size_t)256 * 512 * 2);
  unsigned short* z    = (unsigned short*)alloc((size_t)BATCH * ZDIM * 2);
  unsigned short* z1   = (unsigned short*)alloc((size_t)BATCH * 512 * 2);

  // mega: cast(tw0,tw1) + bottom MLP (z[:,0:64]) + embedding (z[:,64:])
  {
    MegaArgs a;
    a.cast_s[0] = tw0; a.cast_d[0] = tw0b; a.cast_n4[0] = 512 * ZDIM / 4;
    a.cast_s[1] = tw1; a.cast_d[1] = tw1b; a.cast_n4[1] = 256 * 512 / 4;
    a.cast_total = a.cast_n4[0] + a.cast_n4[1];
    a.x_dense = x_dense;
    a.bw0 = bw0; a.bb0 = bb0;
    a.bw1 = bw1; a.bb1 = bb1;
    a.bw2 = bw2; a.bb2 = bb2;
    a.idx = x_idx;
    a.tables = tables;
    a.z = z;
    mega<<<CAST_BLOCKS + BOT_BLOCKS + EMBED_BLOCKS, 256, 0, stream>>>(a);
  }

  // top0: z1 = relu(z @ tw0b^T + tb0)  [M=4096, N=512, K=1728] -> 512 blocks
  gemm64s<1><<<512, 256, 0, stream>>>(z, tw0b, tb0, z1, BATCH, 512, ZDIM, 512);

  // top1 + final fused
  topfin256<<<BATCH / 16, 256, 0, stream>>>(z1, tw1b, tb1, tw2, tb2, out);
}